// Round 6
// baseline (222.723 us; speedup 1.0000x reference)
//
#include <hip/hip_runtime.h>

constexpr int NFEAT  = 256;
constexpr int NHID   = 128;
constexpr int NCLASS = 64;

typedef __attribute__((ext_vector_type(8))) short short8;   // 8 bf16 (4 VGPRs)
typedef __attribute__((ext_vector_type(4))) float floatx4;  // MFMA accumulator

__device__ __forceinline__ unsigned short f2bf(float x) {
    unsigned u = __float_as_uint(x);
    u += 0x7FFFu + ((u >> 16) & 1u);   // RNE
    return (unsigned short)(u >> 16);
}
__device__ __forceinline__ float bf_lo(unsigned int p) { return __uint_as_float(p << 16); }
__device__ __forceinline__ float bf_hi(unsigned int p) { return __uint_as_float(p & 0xFFFF0000u); }

// ---------------- W pre-cast + transpose: W[K][N] f32 -> WT[N][K] bf16 ----------------
__global__ __launch_bounds__(256) void cast_w_kernel(
    const float* __restrict__ W1, const float* __restrict__ W2,
    unsigned short* __restrict__ W1T, unsigned short* __restrict__ W2T)
{
    int i = blockIdx.x * 256 + threadIdx.x;
    if (i < NFEAT * NHID) {         // 256x128
        int k = i >> 7, n = i & 127;
        W1T[n * NFEAT + k] = f2bf(W1[i]);
    }
    if (i < NHID * NCLASS) {        // 128x64
        int k = i >> 6, n = i & 63;
        W2T[n * NHID + k] = f2bf(W2[i]);
    }
}

// ---------------- MFMA GEMM: C[M][BN] bf16 = A[M][KTOT] @ BT^T ----------------
// BM=128, BK=64. Waves in WRxWC grid (WR*WC=4). XOR-swizzled LDS (G4),
// register-prefetch of next K-tile (T14: issue-early / LDS-write-late).
template<int BN, int KTOT, bool A_IS_F32, int WR, int WC>
__global__ __launch_bounds__(256) void gemm_mfma_kernel(
    const void* __restrict__ Aptr,
    const unsigned short* __restrict__ BT,
    unsigned short* __restrict__ C,
    int M)
{
    constexpr int BM  = 128;
    constexpr int MF  = BM / (WR * 16);     // row frags per wave
    constexpr int NF  = BN / (WC * 16);     // col frags per wave
    constexpr int NKT = KTOT / 64;
    constexpr int CA  = BM * 8 / 256;       // A 16B-chunks per thread (4)
    constexpr int CB  = BN * 8 / 256;       // B 16B-chunks per thread (4 or 2)
    __shared__ unsigned short As[BM * 64];  // swizzled, 128B row stride
    __shared__ unsigned short Bs[BN * 64];

    const int tid = threadIdx.x;
    const int w = tid >> 6, l = tid & 63;
    const int wr = w / WC, wc = w % WC;
    const int wrow = wr * (BM / WR), wcol = wc * (BN / WC);
    const int row0 = blockIdx.x * BM;

    floatx4 acc[MF][NF];
    #pragma unroll
    for (int i = 0; i < MF; ++i)
        #pragma unroll
        for (int j = 0; j < NF; ++j) acc[i][j] = (floatx4){0.f, 0.f, 0.f, 0.f};

    float4 pa[CA][2];   // f32 A prefetch (packed at store time)
    uint4  pa16[CA];    // bf16 A prefetch
    uint4  pb[CB];

    auto load_tile = [&](int k0) {
        #pragma unroll
        for (int i = 0; i < CA; ++i) {
            int c = tid + 256 * i;
            int r = c >> 3, kb = c & 7;
            int row = row0 + r;
            if constexpr (A_IS_F32) {
                const float* A = (const float*)Aptr;
                if (row < M) {
                    const float* p = A + (size_t)row * KTOT + k0 + kb * 8;
                    pa[i][0] = *reinterpret_cast<const float4*>(p);
                    pa[i][1] = *reinterpret_cast<const float4*>(p + 4);
                } else {
                    pa[i][0] = make_float4(0.f, 0.f, 0.f, 0.f);
                    pa[i][1] = make_float4(0.f, 0.f, 0.f, 0.f);
                }
            } else {
                const unsigned short* A = (const unsigned short*)Aptr;
                pa16[i] = (row < M)
                    ? *reinterpret_cast<const uint4*>(A + (size_t)row * KTOT + k0 + kb * 8)
                    : make_uint4(0u, 0u, 0u, 0u);
            }
        }
        #pragma unroll
        for (int i = 0; i < CB; ++i) {
            int c = tid + 256 * i;
            int n = c >> 3, kb = c & 7;
            pb[i] = *reinterpret_cast<const uint4*>(BT + (size_t)n * KTOT + k0 + kb * 8);
        }
    };
    auto store_tile = [&]() {
        #pragma unroll
        for (int i = 0; i < CA; ++i) {
            int c = tid + 256 * i;
            int r = c >> 3, kb = c & 7;
            uint4 v;
            if constexpr (A_IS_F32) {
                v.x = (unsigned)f2bf(pa[i][0].x) | ((unsigned)f2bf(pa[i][0].y) << 16);
                v.y = (unsigned)f2bf(pa[i][0].z) | ((unsigned)f2bf(pa[i][0].w) << 16);
                v.z = (unsigned)f2bf(pa[i][1].x) | ((unsigned)f2bf(pa[i][1].y) << 16);
                v.w = (unsigned)f2bf(pa[i][1].z) | ((unsigned)f2bf(pa[i][1].w) << 16);
            } else {
                v = pa16[i];
            }
            *reinterpret_cast<uint4*>(&As[r * 64 + ((kb ^ (r & 7)) * 8)]) = v;
        }
        #pragma unroll
        for (int i = 0; i < CB; ++i) {
            int c = tid + 256 * i;
            int n = c >> 3, kb = c & 7;
            *reinterpret_cast<uint4*>(&Bs[n * 64 + ((kb ^ (n & 7)) * 8)]) = pb[i];
        }
    };

    load_tile(0);
    store_tile();
    __syncthreads();
    for (int kt = 0; kt < NKT; ++kt) {
        if (kt + 1 < NKT) load_tile((kt + 1) * 64);   // issue next-tile loads early
        #pragma unroll
        for (int ks = 0; ks < 2; ++ks) {
            const int kb = ks * 4 + (l >> 4);
            short8 af[MF];
            #pragma unroll
            for (int mf = 0; mf < MF; ++mf) {
                int r = wrow + mf * 16 + (l & 15);
                af[mf] = *reinterpret_cast<const short8*>(&As[r * 64 + ((kb ^ (r & 7)) * 8)]);
            }
            #pragma unroll
            for (int nf = 0; nf < NF; ++nf) {
                int n = wcol + nf * 16 + (l & 15);
                short8 bf = *reinterpret_cast<const short8*>(&Bs[n * 64 + ((kb ^ (n & 7)) * 8)]);
                #pragma unroll
                for (int mf = 0; mf < MF; ++mf)
                    acc[mf][nf] = __builtin_amdgcn_mfma_f32_16x16x32_bf16(af[mf], bf, acc[mf][nf], 0, 0, 0);
            }
        }
        __syncthreads();                               // all waves done reading
        if (kt + 1 < NKT) { store_tile(); __syncthreads(); }
    }
    // epilogue: C/D layout col = lane&15, row = (lane>>4)*4 + reg
    const int cr = (l >> 4) * 4, cc = l & 15;
    #pragma unroll
    for (int mf = 0; mf < MF; ++mf)
        #pragma unroll
        for (int nf = 0; nf < NF; ++nf)
            #pragma unroll
            for (int r = 0; r < 4; ++r) {
                int row = row0 + wrow + mf * 16 + cr + r;
                if (row < M) C[(size_t)row * BN + wcol + nf * 16 + cc] = f2bf(acc[mf][nf][r]);
            }
}

// ---------------- two-level CSR build (coalesced writes) ----------------
// bucket b = dst >> 8 (256 rows per bucket); nbuk <= 512; pack = src | (dst&255)<<17

constexpr int EPB = 8192;   // edges per partition block

__global__ __launch_bounds__(256) void bucket_count_kernel(
    const int* __restrict__ dst, int* __restrict__ bcnt, int E, int nbuk)
{
    __shared__ int cnt[512];
    for (int i = threadIdx.x; i < 512; i += 256) cnt[i] = 0;
    __syncthreads();
    int begin = blockIdx.x * EPB;
    int endi = begin + EPB; if (endi > E) endi = E;
    for (int i = begin + threadIdx.x; i < endi; i += 256)
        atomicAdd(&cnt[dst[i] >> 8], 1);
    __syncthreads();
    for (int b = threadIdx.x; b < nbuk; b += 256)
        if (cnt[b]) atomicAdd(&bcnt[b], cnt[b]);
}

__global__ __launch_bounds__(512) void bucket_scan_kernel(
    const int* __restrict__ bcnt, int* __restrict__ bb, int* __restrict__ bcur,
    int* __restrict__ row_ptr, int nbuk, int M, int E)
{
    __shared__ int s[512];
    int t = threadIdx.x;
    int v = (t < nbuk) ? bcnt[t] : 0;
    s[t] = v;
    __syncthreads();
    for (int off = 1; off < 512; off <<= 1) {
        int u = (t >= off) ? s[t - off] : 0;
        __syncthreads();
        s[t] += u;
        __syncthreads();
    }
    if (t < nbuk) {
        int excl = s[t] - v;
        bb[t] = excl;
        bcur[t] = excl;
    }
    if (t == 0) { bb[nbuk] = E; row_ptr[M] = E; }
}

__global__ __launch_bounds__(256) void bucket_scatter_kernel(
    const float* __restrict__ vals, const int* __restrict__ src,
    const int* __restrict__ dst, int* __restrict__ bcur,
    int2* __restrict__ tmp, int E)
{
    __shared__ int cnt[512];
    __shared__ int base[512];
    for (int i = threadIdx.x; i < 512; i += 256) cnt[i] = 0;
    __syncthreads();
    int begin = blockIdx.x * EPB;
    int endi = begin + EPB; if (endi > E) endi = E;
    for (int i = begin + threadIdx.x; i < endi; i += 256)
        atomicAdd(&cnt[dst[i] >> 8], 1);
    __syncthreads();
    for (int b = threadIdx.x; b < 512; b += 256) {
        int c = cnt[b];
        base[b] = c ? atomicAdd(&bcur[b], c) : 0;
        cnt[b] = 0;
    }
    __syncthreads();
    for (int i = begin + threadIdx.x; i < endi; i += 256) {
        int d = dst[i];
        int b = d >> 8;
        int pos = base[b] + atomicAdd(&cnt[b], 1);
        tmp[pos] = make_int2(src[i] | ((d & 255) << 17), __float_as_int(vals[i]));
    }
}

__global__ __launch_bounds__(256) void bucket_fine_kernel(
    const int* __restrict__ bb, const int2* __restrict__ tmp,
    int* __restrict__ row_ptr, int2* __restrict__ pairs, int M)
{
    __shared__ int cnt[256];
    __shared__ int excl[256];
    __shared__ int cur[256];
    const int b = blockIdx.x;
    const int beg = bb[b], endi = bb[b + 1];
    const int t = threadIdx.x;
    cnt[t] = 0;
    __syncthreads();
    for (int j = beg + t; j < endi; j += 256)
        atomicAdd(&cnt[(tmp[j].x >> 17) & 255], 1);
    __syncthreads();
    int v = cnt[t];
    excl[t] = v;
    __syncthreads();
    for (int off = 1; off < 256; off <<= 1) {
        int u = (t >= off) ? excl[t - off] : 0;
        __syncthreads();
        excl[t] += u;
        __syncthreads();
    }
    int ex = excl[t] - v;
    excl[t] = ex;
    cur[t] = 0;
    int row = (b << 8) + t;
    if (row < M) row_ptr[row] = beg + ex;
    __syncthreads();
    for (int j = beg + t; j < endi; j += 256) {
        int2 p = tmp[j];
        int dl = (p.x >> 17) & 255;
        int pos = beg + excl[dl] + atomicAdd(&cur[dl], 1);
        pairs[pos] = p;
    }
}

// ---------------- gather SPMM, bf16 dense, 16/8-lane row groups ----------------

// D=128: 16-lane group per dst row (4 rows/wave, 16 rows/block). Output: relu -> bf16.
__global__ __launch_bounds__(256) void spmm_gather128_kernel(
    const int*  __restrict__ row_ptr,
    const int2* __restrict__ pairs,
    const unsigned short* __restrict__ dense,   // bf16 [M][128]
    unsigned short*       __restrict__ outbf,   // bf16 [M][128] = relu(sum)
    int M)
{
    const int wv = threadIdx.x >> 6, l = threadIdx.x & 63;
    const int g = l >> 4, t = l & 15;
    const int row = blockIdx.x * 16 + wv * 4 + g;
    int beg = 0, end = 0;
    if (row < M) { beg = row_ptr[row]; end = row_ptr[row + 1]; }
    const uint4* d4 = reinterpret_cast<const uint4*>(dense);  // row = 16 uint4
    float2 a0 = {0.f, 0.f}, a1 = {0.f, 0.f}, a2 = {0.f, 0.f}, a3 = {0.f, 0.f};
    int j = beg;
    for (; j + 4 <= end; j += 4) {
        int2 p0 = pairs[j], p1 = pairs[j + 1], p2 = pairs[j + 2], p3 = pairs[j + 3];
        uint4 x0 = d4[(size_t)(p0.x & 0x1FFFF) * 16 + t];
        uint4 x1 = d4[(size_t)(p1.x & 0x1FFFF) * 16 + t];
        uint4 x2 = d4[(size_t)(p2.x & 0x1FFFF) * 16 + t];
        uint4 x3 = d4[(size_t)(p3.x & 0x1FFFF) * 16 + t];
        float v0 = __int_as_float(p0.y), v1 = __int_as_float(p1.y);
        float v2 = __int_as_float(p2.y), v3 = __int_as_float(p3.y);
        a0.x += v0 * bf_lo(x0.x); a0.y += v0 * bf_hi(x0.x);
        a1.x += v0 * bf_lo(x0.y); a1.y += v0 * bf_hi(x0.y);
        a2.x += v0 * bf_lo(x0.z); a2.y += v0 * bf_hi(x0.z);
        a3.x += v0 * bf_lo(x0.w); a3.y += v0 * bf_hi(x0.w);
        a0.x += v1 * bf_lo(x1.x); a0.y += v1 * bf_hi(x1.x);
        a1.x += v1 * bf_lo(x1.y); a1.y += v1 * bf_hi(x1.y);
        a2.x += v1 * bf_lo(x1.z); a2.y += v1 * bf_hi(x1.z);
        a3.x += v1 * bf_lo(x1.w); a3.y += v1 * bf_hi(x1.w);
        a0.x += v2 * bf_lo(x2.x); a0.y += v2 * bf_hi(x2.x);
        a1.x += v2 * bf_lo(x2.y); a1.y += v2 * bf_hi(x2.y);
        a2.x += v2 * bf_lo(x2.z); a2.y += v2 * bf_hi(x2.z);
        a3.x += v2 * bf_lo(x2.w); a3.y += v2 * bf_hi(x2.w);
        a0.x += v3 * bf_lo(x3.x); a0.y += v3 * bf_hi(x3.x);
        a1.x += v3 * bf_lo(x3.y); a1.y += v3 * bf_hi(x3.y);
        a2.x += v3 * bf_lo(x3.z); a2.y += v3 * bf_hi(x3.z);
        a3.x += v3 * bf_lo(x3.w); a3.y += v3 * bf_hi(x3.w);
    }
    for (; j < end; ++j) {
        int2 p = pairs[j];
        uint4 x = d4[(size_t)(p.x & 0x1FFFF) * 16 + t];
        float v = __int_as_float(p.y);
        a0.x += v * bf_lo(x.x); a0.y += v * bf_hi(x.x);
        a1.x += v * bf_lo(x.y); a1.y += v * bf_hi(x.y);
        a2.x += v * bf_lo(x.z); a2.y += v * bf_hi(x.z);
        a3.x += v * bf_lo(x.w); a3.y += v * bf_hi(x.w);
    }
    if (row < M) {
        uint4 o;
        o.x = (unsigned)f2bf(fmaxf(a0.x, 0.f)) | ((unsigned)f2bf(fmaxf(a0.y, 0.f)) << 16);
        o.y = (unsigned)f2bf(fmaxf(a1.x, 0.f)) | ((unsigned)f2bf(fmaxf(a1.y, 0.f)) << 16);
        o.z = (unsigned)f2bf(fmaxf(a2.x, 0.f)) | ((unsigned)f2bf(fmaxf(a2.y, 0.f)) << 16);
        o.w = (unsigned)f2bf(fmaxf(a3.x, 0.f)) | ((unsigned)f2bf(fmaxf(a3.y, 0.f)) << 16);
        reinterpret_cast<uint4*>(outbf)[(size_t)row * 16 + t] = o;
    }
}

// D=64: 8-lane group per dst row (8 rows/wave, 32 rows/block). Output f32.
__global__ __launch_bounds__(256) void spmm_gather64_kernel(
    const int*  __restrict__ row_ptr,
    const int2* __restrict__ pairs,
    const unsigned short* __restrict__ dense,   // bf16 [M][64]
    float*                __restrict__ out,     // f32 [M][64]
    int M)
{
    const int wv = threadIdx.x >> 6, l = threadIdx.x & 63;
    const int g = l >> 3, t = l & 7;
    const int row = blockIdx.x * 32 + wv * 8 + g;
    int beg = 0, end = 0;
    if (row < M) { beg = row_ptr[row]; end = row_ptr[row + 1]; }
    const uint4* d4 = reinterpret_cast<const uint4*>(dense);  // row = 8 uint4
    float2 a0 = {0.f, 0.f}, a1 = {0.f, 0.f}, a2 = {0.f, 0.f}, a3 = {0.f, 0.f};
    int j = beg;
    for (; j + 4 <= end; j += 4) {
        int2 p0 = pairs[j], p1 = pairs[j + 1], p2 = pairs[j + 2], p3 = pairs[j + 3];
        uint4 x0 = d4[(size_t)(p0.x & 0x1FFFF) * 8 + t];
        uint4 x1 = d4[(size_t)(p1.x & 0x1FFFF) * 8 + t];
        uint4 x2 = d4[(size_t)(p2.x & 0x1FFFF) * 8 + t];
        uint4 x3 = d4[(size_t)(p3.x & 0x1FFFF) * 8 + t];
        float v0 = __int_as_float(p0.y), v1 = __int_as_float(p1.y);
        float v2 = __int_as_float(p2.y), v3 = __int_as_float(p3.y);
        a0.x += v0 * bf_lo(x0.x); a0.y += v0 * bf_hi(x0.x);
        a1.x += v0 * bf_lo(x0.y); a1.y += v0 * bf_hi(x0.y);
        a2.x += v0 * bf_lo(x0.z); a2.y += v0 * bf_hi(x0.z);
        a3.x += v0 * bf_lo(x0.w); a3.y += v0 * bf_hi(x0.w);
        a0.x += v1 * bf_lo(x1.x); a0.y += v1 * bf_hi(x1.x);
        a1.x += v1 * bf_lo(x1.y); a1.y += v1 * bf_hi(x1.y);
        a2.x += v1 * bf_lo(x1.z); a2.y += v1 * bf_hi(x1.z);
        a3.x += v1 * bf_lo(x1.w); a3.y += v1 * bf_hi(x1.w);
        a0.x += v2 * bf_lo(x2.x); a0.y += v2 * bf_hi(x2.x);
        a1.x += v2 * bf_lo(x2.y); a1.y += v2 * bf_hi(x2.y);
        a2.x += v2 * bf_lo(x2.z); a2.y += v2 * bf_hi(x2.z);
        a3.x += v2 * bf_lo(x2.w); a3.y += v2 * bf_hi(x2.w);
        a0.x += v3 * bf_lo(x3.x); a0.y += v3 * bf_hi(x3.x);
        a1.x += v3 * bf_lo(x3.y); a1.y += v3 * bf_hi(x3.y);
        a2.x += v3 * bf_lo(x3.z); a2.y += v3 * bf_hi(x3.z);
        a3.x += v3 * bf_lo(x3.w); a3.y += v3 * bf_hi(x3.w);
    }
    for (; j < end; ++j) {
        int2 p = pairs[j];
        uint4 x = d4[(size_t)(p.x & 0x1FFFF) * 8 + t];
        float v = __int_as_float(p.y);
        a0.x += v * bf_lo(x.x); a0.y += v * bf_hi(x.x);
        a1.x += v * bf_lo(x.y); a1.y += v * bf_hi(x.y);
        a2.x += v * bf_lo(x.z); a2.y += v * bf_hi(x.z);
        a3.x += v * bf_lo(x.w); a3.y += v * bf_hi(x.w);
    }
    if (row < M) {
        float4 o0 = make_float4(a0.x, a0.y, a1.x, a1.y);
        float4 o1 = make_float4(a2.x, a2.y, a3.x, a3.y);
        float4* op = reinterpret_cast<float4*>(out + (size_t)row * 64 + t * 8);
        op[0] = o0;
        op[1] = o1;
    }
}

extern "C" void kernel_launch(void* const* d_in, const int* in_sizes, int n_in,
                              void* d_out, int out_size, void* d_ws, size_t ws_size,
                              hipStream_t stream) {
    const float* x  = (const float*)d_in[0];
    const float* W1 = (const float*)d_in[1];
    const float* W2 = (const float*)d_in[2];
    const float* ev = (const float*)d_in[3];
    const int*   es = (const int*)d_in[4];
    const int*   ed = (const int*)d_in[5];
    float* out = (float*)d_out;

    const int M = in_sizes[0] / NFEAT;   // 100000
    const int E = in_sizes[3];           // 1.6M
    const int nbuk = (M + 255) >> 8;     // 391

    size_t off = 0;
    auto alloc = [&](size_t bytes) -> void* {
        void* p = (char*)d_ws + off;
        off += (bytes + 255) & ~(size_t)255;
        return p;
    };
    unsigned short* sup_bf  = (unsigned short*)alloc((size_t)M * NHID * 2);
    unsigned short* h_bf    = (unsigned short*)alloc((size_t)M * NHID * 2);
    unsigned short* sup2_bf = (unsigned short*)alloc((size_t)M * NCLASS * 2);
    unsigned short* W1T     = (unsigned short*)alloc((size_t)NHID * NFEAT * 2);
    unsigned short* W2T     = (unsigned short*)alloc((size_t)NCLASS * NHID * 2);
    int*  row_ptr = (int*) alloc((size_t)(M + 1) * sizeof(int));
    int*  bcnt    = (int*) alloc(512 * sizeof(int));
    int*  bb      = (int*) alloc(513 * sizeof(int));
    int*  bcur    = (int*) alloc(512 * sizeof(int));
    int2* tmp     = (int2*)alloc((size_t)E * sizeof(int2));
    int2* pairs   = (int2*)alloc((size_t)E * sizeof(int2));
    (void)ws_size;

    const int pgrid = (E + EPB - 1) / EPB;

    cast_w_kernel<<<(NFEAT * NHID + 255) / 256, 256, 0, stream>>>(W1, W2, W1T, W2T);

    // GEMM1: 128x128 tile, 2x2 waves (64x64 each)
    gemm_mfma_kernel<NHID, NFEAT, true, 2, 2><<<(M + 127) / 128, 256, 0, stream>>>(x, W1T, sup_bf, M);

    hipMemsetAsync(bcnt, 0, 512 * sizeof(int), stream);
    bucket_count_kernel<<<pgrid, 256, 0, stream>>>(ed, bcnt, E, nbuk);
    bucket_scan_kernel<<<1, 512, 0, stream>>>(bcnt, bb, bcur, row_ptr, nbuk, M, E);
    bucket_scatter_kernel<<<pgrid, 256, 0, stream>>>(ev, es, ed, bcur, tmp, E);
    bucket_fine_kernel<<<nbuk, 256, 0, stream>>>(bb, tmp, row_ptr, pairs, M);

    spmm_gather128_kernel<<<(M + 15) / 16, 256, 0, stream>>>(row_ptr, pairs, sup_bf, h_bf, M);

    // GEMM2: 128x64 tile, 4x1 waves (32x64 each)
    gemm_mfma_kernel<NCLASS, NHID, false, 4, 1><<<(M + 127) / 128, 256, 0, stream>>>(h_bf, W2T, sup2_bf, M);

    spmm_gather64_kernel<<<(M + 31) / 32, 256, 0, stream>>>(row_ptr, pairs, sup2_bf, out, M);
}